// Round 11
// baseline (327.146 us; speedup 1.0000x reference)
//
#include <hip/hip_runtime.h>
#include <stdint.h>

#define D_DIM 4096
#define V_DIM 32000
#define B_SEQ 64
#define MAXC 2048
#define SPLITK 4
#define KCH 1024   // K per chunk

typedef __attribute__((ext_vector_type(8))) short short8;
typedef __attribute__((ext_vector_type(4))) float f32x4;

// ---- ws layout (float units) ----
#define H1_OFF     0u
#define H2_OFF     131072u
#define H3_OFF     262144u
#define LOGITS_OFF 393216u                     // 64*32000
#define PART_OFF   2441216u                    // 4 * 64*32000

// async global->LDS, 16B per lane, linear dest (wave-uniform base + lane*16)
#define GLD16(gsrc, ldst) \
    __builtin_amdgcn_global_load_lds((const __attribute__((address_space(1))) unsigned*)(gsrc), \
                                     (__attribute__((address_space(3))) unsigned*)(ldst), 16, 0, 0)

__device__ __forceinline__ unsigned f2key(float x) {
    unsigned u = __float_as_uint(x);
    return (u & 0x80000000u) ? ~u : (u | 0x80000000u);
}
__device__ __forceinline__ float key2f(unsigned k) {
    unsigned u = (k & 0x80000000u) ? (k & 0x7FFFFFFFu) : ~k;
    return __uint_as_float(u);
}
// exact truncation split: x == l1 + l2 + l3
__device__ __forceinline__ void split3(float x, ushort& a, ushort& b, ushort& c) {
    unsigned u = __float_as_uint(x);
    a = (ushort)(u >> 16);
    float r1 = x - __uint_as_float(u & 0xFFFF0000u);
    unsigned u2 = __float_as_uint(r1);
    b = (ushort)(u2 >> 16);
    float r2 = r1 - __uint_as_float(u2 & 0xFFFF0000u);
    c = (ushort)(__float_as_uint(r2) >> 16);
}

// ---- gather last-token rows + split into 3 exact bf16 limbs ----
__global__ void k_prep(const float* __restrict__ hs, const int* __restrict__ lti,
                       ushort* __restrict__ h1, ushort* __restrict__ h2,
                       ushort* __restrict__ h3) {
    int b = blockIdx.x;
    const float4* src = (const float4*)(hs + (size_t)lti[b] * D_DIM);
    ushort4* d1 = (ushort4*)(h1 + (size_t)b * D_DIM);
    ushort4* d2 = (ushort4*)(h2 + (size_t)b * D_DIM);
    ushort4* d3 = (ushort4*)(h3 + (size_t)b * D_DIM);
    for (int i = threadIdx.x; i < D_DIM / 4; i += blockDim.x) {
        float4 v = src[i];
        float x[4] = {v.x, v.y, v.z, v.w};
        ushort l1[4], l2[4], l3[4];
#pragma unroll
        for (int j = 0; j < 4; ++j) split3(x[j], l1[j], l2[j], l3[j]);
        d1[i] = make_ushort4(l1[0], l1[1], l1[2], l1[3]);
        d2[i] = make_ushort4(l2[0], l2[1], l2[2], l2[3]);
        d3[i] = make_ushort4(l3[0], l3[1], l3[2], l3[3]);
    }
}

__device__ __forceinline__ void splitB(const float4& x0, const float4& x1,
                                       short8& b1, short8& b2, short8& b3) {
    float xf[8] = {x0.x, x0.y, x0.z, x0.w, x1.x, x1.y, x1.z, x1.w};
#pragma unroll
    for (int j = 0; j < 8; ++j) {
        ushort u1, u2, u3;
        split3(xf[j], u1, u2, u3);
        b1[j] = (short)u1; b2[j] = (short)u2; b3[j] = (short)u3;
    }
}

// ---- split-K MFMA GEMM, T3+T4: counted vmcnt, raw barriers, loads stay in flight ----
__global__ __launch_bounds__(256, 2) void k_gemm(const ushort* __restrict__ h1,
                                                 const ushort* __restrict__ h2,
                                                 const ushort* __restrict__ h3,
                                                 const float* __restrict__ emb,
                                                 float* __restrict__ part) {
    __shared__ __align__(16) float  sB[2][4096];   // 2 x 16 KB (64 vocab x 64 k fp32)
    __shared__ __align__(16) ushort sA1[2][4096];  // 2 x 8 KB  (64 m x 64 k bf16)
    __shared__ __align__(16) ushort sA2[2][4096];
    __shared__ __align__(16) ushort sA3[2][4096];
    const int tid = threadIdx.x;
    const int w = tid >> 6, lane = tid & 63, lrow = lane & 15, q = lane >> 4;
    const int kc = blockIdx.y;
    const int vbase = blockIdx.x * 64;
    const int vrow = vbase + w * 16 + lrow;
    const size_t kbase = (size_t)kc * KCH;

    f32x4 acc[4];
#pragma unroll
    for (int mf = 0; mf < 4; ++mf)
#pragma unroll
        for (int r = 0; r < 4; ++r) acc[mf][r] = 0.f;

    // ---- staging descriptors (per-lane pre-swizzled global sources) ----
    const float* srcB[4];
#pragma unroll
    for (int j = 0; j < 4; ++j) {
        int row = w * 4 + j * 16 + (lane >> 4);
        unsigned c16 = (((unsigned)(lane & 15)) << 4) ^ (((unsigned)(row & 7)) << 4);
        srcB[j] = emb + (size_t)(vbase + row) * D_DIM + kbase + (c16 >> 2);
    }
    const ushort* srcA1[2]; const ushort* srcA2[2]; const ushort* srcA3[2];
#pragma unroll
    for (int j = 0; j < 2; ++j) {
        int row = w * 8 + j * 32 + (lane >> 3);
        unsigned c16 = (((unsigned)(lane & 7)) << 4) ^ (((unsigned)(row & 7)) << 4);
        size_t off = (size_t)row * D_DIM + kbase + (c16 >> 1);
        srcA1[j] = h1 + off; srcA2[j] = h2 + off; srcA3[j] = h3 + off;
    }
    const unsigned brow = (unsigned)(w * 16 + lrow);
    const unsigned bswz = (brow & 7u) << 4;
    const unsigned ldst = (unsigned)(w * 1024);

#define STAGE(nb, kk) do { \
        GLD16(srcB[0] + (kk), (char*)&sB[nb][0]  + ldst + 0);     \
        GLD16(srcB[1] + (kk), (char*)&sB[nb][0]  + ldst + 4096);  \
        GLD16(srcB[2] + (kk), (char*)&sB[nb][0]  + ldst + 8192);  \
        GLD16(srcB[3] + (kk), (char*)&sB[nb][0]  + ldst + 12288); \
        GLD16(srcA1[0] + (kk), (char*)&sA1[nb][0] + ldst + 0);    \
        GLD16(srcA1[1] + (kk), (char*)&sA1[nb][0] + ldst + 4096); \
        GLD16(srcA2[0] + (kk), (char*)&sA2[nb][0] + ldst + 0);    \
        GLD16(srcA2[1] + (kk), (char*)&sA2[nb][0] + ldst + 4096); \
        GLD16(srcA3[0] + (kk), (char*)&sA3[nb][0] + ldst + 0);    \
        GLD16(srcA3[1] + (kk), (char*)&sA3[nb][0] + ldst + 4096); \
    } while (0)

#define COMPUTE_TILE(cur) do {                                                        \
        _Pragma("unroll")                                                             \
        for (int s = 0; s < 2; ++s) {                                                 \
            unsigned binner = (unsigned)(s * 128 + q * 32);                           \
            const char* bb = (const char*)&sB[cur][0] + brow * 256u;                  \
            float4 bf0 = *(const float4*)(bb + (binner ^ bswz));                      \
            float4 bf1 = *(const float4*)(bb + ((binner + 16u) ^ bswz));              \
            short8 vb1, vb2, vb3;                                                     \
            splitB(bf0, bf1, vb1, vb2, vb3);                                          \
            __builtin_amdgcn_s_setprio(1);                                            \
            _Pragma("unroll")                                                         \
            for (int mf = 0; mf < 4; ++mf) {                                          \
                unsigned arow = (unsigned)(mf * 16 + lrow);                           \
                unsigned abyte = arow * 128u                                          \
                               + (((unsigned)(s * 64 + q * 16)) ^ ((arow & 7u) << 4));\
                short8 a1 = *(const short8*)((const char*)&sA1[cur][0] + abyte);      \
                short8 a2 = *(const short8*)((const char*)&sA2[cur][0] + abyte);      \
                short8 a3 = *(const short8*)((const char*)&sA3[cur][0] + abyte);      \
                acc[mf] = __builtin_amdgcn_mfma_f32_16x16x32_bf16(a1, vb1, acc[mf], 0, 0, 0); \
                acc[mf] = __builtin_amdgcn_mfma_f32_16x16x32_bf16(a1, vb2, acc[mf], 0, 0, 0); \
                acc[mf] = __builtin_amdgcn_mfma_f32_16x16x32_bf16(a2, vb1, acc[mf], 0, 0, 0); \
                acc[mf] = __builtin_amdgcn_mfma_f32_16x16x32_bf16(a2, vb2, acc[mf], 0, 0, 0); \
                acc[mf] = __builtin_amdgcn_mfma_f32_16x16x32_bf16(a1, vb3, acc[mf], 0, 0, 0); \
                acc[mf] = __builtin_amdgcn_mfma_f32_16x16x32_bf16(a3, vb1, acc[mf], 0, 0, 0); \
            }                                                                         \
            __builtin_amdgcn_s_setprio(0);                                            \
        }                                                                             \
    } while (0)

    // ---- prologue: tile 0 in flight (10 outstanding) ----
    STAGE(0, 0);

    // ---- main loop: tiles 0..14; counted vmcnt keeps next tile's loads in flight ----
    for (int k0 = 0; k0 < KCH - 64; k0 += 64) {
        const int cur = (k0 >> 6) & 1;
        STAGE(cur ^ 1, k0 + 64);                       // 20 outstanding
        asm volatile("s_waitcnt vmcnt(10)" ::: "memory");   // oldest 10 (tile cur) done
        __builtin_amdgcn_sched_barrier(0);
        __builtin_amdgcn_s_barrier();                  // everyone's tile-cur loads landed
        __builtin_amdgcn_sched_barrier(0);
        COMPUTE_TILE(cur);
        __builtin_amdgcn_sched_barrier(0);
        __builtin_amdgcn_s_barrier();                  // all reads of cur done before overwrite
    }
    // ---- epilogue: last tile (buf 1) ----
    asm volatile("s_waitcnt vmcnt(0)" ::: "memory");
    __builtin_amdgcn_sched_barrier(0);
    __builtin_amdgcn_s_barrier();
    __builtin_amdgcn_sched_barrier(0);
    COMPUTE_TILE(1);
#undef STAGE
#undef COMPUTE_TILE

    float* pout = part + (size_t)kc * (B_SEQ * V_DIM);
#pragma unroll
    for (int mf = 0; mf < 4; ++mf)
#pragma unroll
        for (int r = 0; r < 4; ++r) {
            int m = mf * 16 + q * 4 + r;
            pout[(size_t)m * V_DIM + vrow] = acc[mf][r];
        }
}

__device__ __forceinline__ float4 f4add(float4 a, float4 b) {
    return make_float4(a.x + b.x, a.y + b.y, a.z + b.z, a.w + b.w);
}

// ---- deterministic split-K reduce + temperature divide + out_probs zeroing ----
__global__ void k_reduce(const float* __restrict__ part,
                         const float* __restrict__ temps,
                         float* __restrict__ logits,
                         float* __restrict__ out_probs) {
    const int b = blockIdx.y;
    float t = temps[b];
    if (t < 1e-5f) t = 1.0f;
    const float inv = 1.0f / t;
    const float4* p0 = (const float4*)(part + 0 * (size_t)(B_SEQ * V_DIM) + (size_t)b * V_DIM);
    const float4* p1 = (const float4*)(part + 1 * (size_t)(B_SEQ * V_DIM) + (size_t)b * V_DIM);
    const float4* p2 = (const float4*)(part + 2 * (size_t)(B_SEQ * V_DIM) + (size_t)b * V_DIM);
    const float4* p3 = (const float4*)(part + 3 * (size_t)(B_SEQ * V_DIM) + (size_t)b * V_DIM);
    float4* lo = (float4*)(logits + (size_t)b * V_DIM);
    float4* po = (float4*)(out_probs + (size_t)b * V_DIM);
    const float4 z4 = make_float4(0.f, 0.f, 0.f, 0.f);
    for (int i = blockIdx.x * 256 + threadIdx.x; i < V_DIM / 4; i += 2048) {
        float4 s = f4add(f4add(f4add(p0[i], p1[i]), p2[i]), p3[i]);
        lo[i] = make_float4(s.x * inv, s.y * inv, s.z * inv, s.w * inv);
        po[i] = z4;
    }
}

// ---- fused per-row: max/Z + radix-select + gather + sort + top-p + sample ----
__global__ __launch_bounds__(512) void k_sample(const float* __restrict__ logits,
                                                const int* __restrict__ tks,
                                                const float* __restrict__ tps,
                                                const float* __restrict__ uu,
                                                float* __restrict__ out_tok,
                                                float* __restrict__ out_probs) {
    const int b = blockIdx.x, t = threadIdx.x;
    const float* lr = logits + (size_t)b * V_DIM;
    __shared__ unsigned hist[2048];
    __shared__ unsigned redu[512];
    __shared__ float redf[512];
    __shared__ unsigned long long cand[MAXC];
    __shared__ float sp[MAXC];
    __shared__ unsigned s_sel1, s_ab1, s_thr, s_nc, s_ab2, s_kthkey;
    __shared__ float s_m, s_Z, s_tot;
    __shared__ int s_cnt, s_L, s_tok, s_nk;

    int k = tks[b];
    if (k < 1) k = 1;
    if (k > V_DIM) k = V_DIM;

    // ---- pass A: max + top-11-bit histogram ----
    for (int i = t; i < 2048; i += 512) hist[i] = 0u;
    __syncthreads();
    unsigned km = 0u;
    for (int v = t; v < V_DIM; v += 512) {
        unsigned key = f2key(lr[v]);
        km = max(km, key);
        atomicAdd(&hist[key >> 21], 1u);
    }
    redu[t] = km;
    __syncthreads();
    for (int s = 256; s > 0; s >>= 1) {
        if (t < s) redu[t] = max(redu[t], redu[t + s]);
        __syncthreads();
    }
    if (t == 0) s_m = key2f(redu[0]);
    __syncthreads();
    float m = s_m;
    redu[t] = hist[4 * t] + hist[4 * t + 1] + hist[4 * t + 2] + hist[4 * t + 3];
    __syncthreads();
    if (t == 0) {
        unsigned acc = 0; int g = 0; bool found = false;
        for (int g0 = 511; g0 >= 0 && !found; g0 -= 8) {
            unsigned v[8];
#pragma unroll
            for (int j = 0; j < 8; ++j) v[j] = redu[g0 - j];
#pragma unroll
            for (int j = 0; j < 8; ++j) {
                if (acc + v[j] >= (unsigned)k) { g = g0 - j; found = true; break; }
                acc += v[j];
            }
        }
        int sel = 4 * g;
        for (int bk = 4 * g + 3; bk >= 4 * g; --bk) {
            unsigned h = hist[bk];
            if (acc + h >= (unsigned)k) { sel = bk; break; }
            acc += h;
        }
        s_sel1 = (unsigned)sel; s_ab1 = acc;
    }
    __syncthreads();
    unsigned sel1 = s_sel1, ab1 = s_ab1;

    // ---- pass B: exp-sum + mid-11-bit histogram within sel1 ----
    for (int i = t; i < 2048; i += 512) hist[i] = 0u;
    __syncthreads();
    float es = 0.f;
    for (int v = t; v < V_DIM; v += 512) {
        float f = lr[v];
        es += expf(f - m);
        unsigned key = f2key(f);
        if ((key >> 21) == sel1) atomicAdd(&hist[(key >> 10) & 2047u], 1u);
    }
    redf[t] = es;
    __syncthreads();
    for (int s = 256; s > 0; s >>= 1) {
        if (t < s) redf[t] += redf[t + s];
        __syncthreads();
    }
    if (t == 0) s_Z = redf[0];
    __syncthreads();
    redu[t] = hist[4 * t] + hist[4 * t + 1] + hist[4 * t + 2] + hist[4 * t + 3];
    __syncthreads();
    if (t == 0) {
        unsigned kk = (unsigned)k - ab1;
        unsigned acc = 0; int g = 0; bool found = false;
        for (int g0 = 511; g0 >= 0 && !found; g0 -= 8) {
            unsigned v[8];
#pragma unroll
            for (int j = 0; j < 8; ++j) v[j] = redu[g0 - j];
#pragma unroll
            for (int j = 0; j < 8; ++j) {
                if (acc + v[j] >= kk) { g = g0 - j; found = true; break; }
                acc += v[j];
            }
        }
        int sel = 4 * g;
        for (int bk = 4 * g + 3; bk >= 4 * g; --bk) {
            unsigned h = hist[bk];
            if (acc + h >= kk) { sel = bk; break; }
            acc += h;
        }
        s_ab2 = ab1 + acc;
        s_thr = (sel1 << 21) | ((unsigned)sel << 10);
        s_nc = ab1 + acc + hist[sel];
    }
    __syncthreads();
    unsigned thr = s_thr;

    // ---- rare pass C: exact kth key if 22-bit bin too fat ----
    if (s_nc > (unsigned)MAXC) {
        for (int i = t; i < 1024; i += 512) hist[i] = 0u;
        __syncthreads();
        for (int v = t; v < V_DIM; v += 512) {
            unsigned key = f2key(lr[v]);
            if ((key & 0xFFFFFC00u) == thr) atomicAdd(&hist[key & 1023u], 1u);
        }
        __syncthreads();
        if (t == 0) {
            unsigned kk = (unsigned)k - s_ab2;
            unsigned acc = 0; int sel = 0;
            for (int bk = 1023; bk >= 0; --bk) {
                unsigned h = hist[bk];
                if (acc + h >= kk) { sel = bk; break; }
                acc += h;
            }
            s_thr = thr | (unsigned)sel;
        }
        __syncthreads();
        thr = s_thr;
    }

    // ---- gather candidates (key >= thr: superset of top-k incl. ties) ----
    if (t == 0) s_cnt = 0;
    for (int i = t; i < MAXC; i += 512) cand[i] = 0xFFFFFFFFFFFFFFFFULL;
    __syncthreads();
    for (int v = t; v < V_DIM; v += 512) {
        unsigned key = f2key(lr[v]);
        if (key >= thr) {
            int p = atomicAdd(&s_cnt, 1);
            if (p < MAXC) cand[p] = (((unsigned long long)(~key)) << 32) | (unsigned)v;
        }
    }
    __syncthreads();
    int n = s_cnt; if (n > MAXC) n = MAXC;
    const int np2 = (n <= 1) ? 1 : (1 << (32 - __clz(n - 1)));

    // ---- bitonic sort of the first np2 entries (key desc, idx asc) ----
    for (unsigned size = 2; size <= (unsigned)np2; size <<= 1)
        for (unsigned stride = size >> 1; stride > 0; stride >>= 1) {
            for (unsigned i = t; i < (unsigned)np2; i += 512) {
                unsigned j = i ^ stride;
                if (j > i) {
                    unsigned long long a = cand[i], c = cand[j];
                    bool up = ((i & size) == 0);
                    if (up ? (a > c) : (a < c)) { cand[i] = c; cand[j] = a; }
                }
            }
            __syncthreads();
        }
    float Z = s_Z;
    for (int i = t; i < n; i += 512) {
        unsigned key = ~(unsigned)(cand[i] >> 32);
        sp[i] = expf(key2f(key) - m) / Z;
    }
    for (int i = n + t; i < MAXC; i += 512) sp[i] = 0.f;
    if (t == 0) s_kthkey = ~(unsigned)(cand[k - 1] >> 32);
    __syncthreads();

    // parallel top-k prefix length incl. ties
    unsigned kthkey = s_kthkey;
    int cnt = 0;
    for (int i = t; i < n; i += 512)
        if ((~(unsigned)(cand[i] >> 32)) >= kthkey) cnt++;
    redu[t] = (unsigned)cnt;
    __syncthreads();
    for (int s = 256; s > 0; s >>= 1) {
        if (t < s) redu[t] += redu[t + s];
        __syncthreads();
    }
    if (t == 0) s_nk = (int)redu[0];
    __syncthreads();

    if (t == 0) {
        float top_p = tps[b];
        bool keepall = (top_p >= 1.0f - 1e-5f);
        int limit = min(n, s_nk);
        // top-p prefix, numpy-sequential fp32, batched LDS preloads
        float c = 0.f; int L = limit; bool done = false;
        for (int i0 = 0; i0 < limit && !done; i0 += 8) {
            float v[8];
#pragma unroll
            for (int j = 0; j < 8; ++j) v[j] = sp[i0 + j];
#pragma unroll
            for (int j = 0; j < 8; ++j) {
                int i = i0 + j;
                if (i >= limit) { done = true; break; }
                float cum = c + v[j];
                if (!keepall && !((cum - v[j]) <= top_p)) { L = i; done = true; break; }
                c = cum;
            }
        }
        float total = c;
        float target = uu[b] * total;
        float c2 = 0.f; int jj = L - 1; done = false;
        for (int i0 = 0; i0 < L && !done; i0 += 8) {
            float v[8];
#pragma unroll
            for (int j = 0; j < 8; ++j) v[j] = sp[i0 + j];
#pragma unroll
            for (int j = 0; j < 8; ++j) {
                int i = i0 + j;
                if (i >= L) { done = true; break; }
                c2 += v[j];
                if (!(c2 < target)) { jj = i; done = true; break; }
            }
        }
        s_tok = (int)(cand[jj] & 0xFFFFFFFFULL);
        s_L = L; s_tot = total;
        out_tok[b] = (float)s_tok;
    }
    __syncthreads();
    int L = s_L; float total = s_tot;
    for (int i = t; i < L; i += 512) {
        unsigned v = (unsigned)(cand[i] & 0xFFFFFFFFULL);
        out_probs[(size_t)b * V_DIM + v] = sp[i] / total;
    }
}

extern "C" void kernel_launch(void* const* d_in, const int* in_sizes, int n_in,
                              void* d_out, int out_size, void* d_ws, size_t ws_size,
                              hipStream_t stream) {
    const float* hs    = (const float*)d_in[0];
    const float* emb   = (const float*)d_in[1];
    const float* temps = (const float*)d_in[2];
    const float* tps   = (const float*)d_in[3];
    const float* uu    = (const float*)d_in[4];
    const int*   lti   = (const int*)d_in[5];
    const int*   tks   = (const int*)d_in[6];

    float* ws = (float*)d_ws;
    ushort* h1 = (ushort*)(ws + H1_OFF);
    ushort* h2 = (ushort*)(ws + H2_OFF);
    ushort* h3 = (ushort*)(ws + H3_OFF);
    float* logits = ws + LOGITS_OFF;
    float* part   = ws + PART_OFF;

    float* out_tok   = (float*)d_out;
    float* out_probs = (float*)d_out + B_SEQ;

    k_prep<<<B_SEQ, 256, 0, stream>>>(hs, lti, h1, h2, h3);
    k_gemm<<<dim3(V_DIM / 64, SPLITK), 256, 0, stream>>>(h1, h2, h3, emb, part);
    k_reduce<<<dim3(8, B_SEQ), 256, 0, stream>>>(part, temps, logits, out_probs);
    k_sample<<<B_SEQ, 512, 0, stream>>>(logits, tks, tps, uu, out_tok, out_probs);
}

// Round 12
// 326.976 us; speedup vs baseline: 1.0005x; 1.0005x over previous
//
#include <hip/hip_runtime.h>
#include <stdint.h>

#define D_DIM 4096
#define V_DIM 32000
#define B_SEQ 64
#define MAXC 2048
#define SPLITK 4
#define KCH 1024   // K per chunk

typedef __attribute__((ext_vector_type(8))) short short8;
typedef __attribute__((ext_vector_type(4))) float f32x4;

// ---- ws layout (float units) ----
#define H1_OFF     0u
#define H2_OFF     131072u
#define H3_OFF     262144u
#define LOGITS_OFF 393216u                     // 64*32000
#define PART_OFF   2441216u                    // 4 * 64*32000

// async global->LDS, 16B per lane, linear dest (wave-uniform base + lane*16)
#define GLD16(gsrc, ldst) \
    __builtin_amdgcn_global_load_lds((const __attribute__((address_space(1))) unsigned*)(gsrc), \
                                     (__attribute__((address_space(3))) unsigned*)(ldst), 16, 0, 0)

__device__ __forceinline__ unsigned f2key(float x) {
    unsigned u = __float_as_uint(x);
    return (u & 0x80000000u) ? ~u : (u | 0x80000000u);
}
__device__ __forceinline__ float key2f(unsigned k) {
    unsigned u = (k & 0x80000000u) ? (k & 0x7FFFFFFFu) : ~k;
    return __uint_as_float(u);
}
// exact truncation split: x == l1 + l2 + l3
__device__ __forceinline__ void split3(float x, ushort& a, ushort& b, ushort& c) {
    unsigned u = __float_as_uint(x);
    a = (ushort)(u >> 16);
    float r1 = x - __uint_as_float(u & 0xFFFF0000u);
    unsigned u2 = __float_as_uint(r1);
    b = (ushort)(u2 >> 16);
    float r2 = r1 - __uint_as_float(u2 & 0xFFFF0000u);
    c = (ushort)(__float_as_uint(r2) >> 16);
}

// ---- gather last-token rows + split into 3 exact bf16 limbs (4 blocks/row) ----
__global__ void k_prep(const float* __restrict__ hs, const int* __restrict__ lti,
                       ushort* __restrict__ h1, ushort* __restrict__ h2,
                       ushort* __restrict__ h3) {
    int b = blockIdx.x >> 2;
    int quarter = blockIdx.x & 3;
    int base = quarter * (D_DIM / 16);   // in float4 units: D/4/4 = 256 per quarter
    const float4* src = (const float4*)(hs + (size_t)lti[b] * D_DIM);
    ushort4* d1 = (ushort4*)(h1 + (size_t)b * D_DIM);
    ushort4* d2 = (ushort4*)(h2 + (size_t)b * D_DIM);
    ushort4* d3 = (ushort4*)(h3 + (size_t)b * D_DIM);
    int i = base + threadIdx.x;
    float4 v = src[i];
    float x[4] = {v.x, v.y, v.z, v.w};
    ushort l1[4], l2[4], l3[4];
#pragma unroll
    for (int j = 0; j < 4; ++j) split3(x[j], l1[j], l2[j], l3[j]);
    d1[i] = make_ushort4(l1[0], l1[1], l1[2], l1[3]);
    d2[i] = make_ushort4(l2[0], l2[1], l2[2], l2[3]);
    d3[i] = make_ushort4(l3[0], l3[1], l3[2], l3[3]);
}

__device__ __forceinline__ void splitB(const float4& x0, const float4& x1,
                                       short8& b1, short8& b2, short8& b3) {
    float xf[8] = {x0.x, x0.y, x0.z, x0.w, x1.x, x1.y, x1.z, x1.w};
#pragma unroll
    for (int j = 0; j < 8; ++j) {
        ushort u1, u2, u3;
        split3(xf[j], u1, u2, u3);
        b1[j] = (short)u1; b2[j] = (short)u2; b3[j] = (short)u3;
    }
}

// ---- split-K MFMA GEMM (r10 measured-best): dbuf LDS, global_load_lds staging ----
__global__ __launch_bounds__(256, 2) void k_gemm(const ushort* __restrict__ h1,
                                                 const ushort* __restrict__ h2,
                                                 const ushort* __restrict__ h3,
                                                 const float* __restrict__ emb,
                                                 float* __restrict__ part) {
    __shared__ __align__(16) float  sB[2][4096];   // 2 x 16 KB (64 vocab x 64 k fp32)
    __shared__ __align__(16) ushort sA1[2][4096];  // 2 x 8 KB  (64 m x 64 k bf16)
    __shared__ __align__(16) ushort sA2[2][4096];
    __shared__ __align__(16) ushort sA3[2][4096];
    const int tid = threadIdx.x;
    const int w = tid >> 6, lane = tid & 63, lrow = lane & 15, q = lane >> 4;
    const int kc = blockIdx.y;
    const int vbase = blockIdx.x * 64;
    const int vrow = vbase + w * 16 + lrow;
    const size_t kbase = (size_t)kc * KCH;

    f32x4 acc[4];
#pragma unroll
    for (int mf = 0; mf < 4; ++mf)
#pragma unroll
        for (int r = 0; r < 4; ++r) acc[mf][r] = 0.f;

    // ---- staging descriptors (per-lane pre-swizzled global sources) ----
    const float* srcB[4];
#pragma unroll
    for (int j = 0; j < 4; ++j) {
        int row = w * 4 + j * 16 + (lane >> 4);
        unsigned c16 = (((unsigned)(lane & 15)) << 4) ^ (((unsigned)(row & 7)) << 4);
        srcB[j] = emb + (size_t)(vbase + row) * D_DIM + kbase + (c16 >> 2);
    }
    const ushort* srcA1[2]; const ushort* srcA2[2]; const ushort* srcA3[2];
#pragma unroll
    for (int j = 0; j < 2; ++j) {
        int row = w * 8 + j * 32 + (lane >> 3);
        unsigned c16 = (((unsigned)(lane & 7)) << 4) ^ (((unsigned)(row & 7)) << 4);
        size_t off = (size_t)row * D_DIM + kbase + (c16 >> 1);
        srcA1[j] = h1 + off; srcA2[j] = h2 + off; srcA3[j] = h3 + off;
    }
    const unsigned brow = (unsigned)(w * 16 + lrow);
    const unsigned bswz = (brow & 7u) << 4;
    const unsigned ldst = (unsigned)(w * 1024);

#define STAGE(nb, kk) do { \
        GLD16(srcB[0] + (kk), (char*)&sB[nb][0]  + ldst + 0);     \
        GLD16(srcB[1] + (kk), (char*)&sB[nb][0]  + ldst + 4096);  \
        GLD16(srcB[2] + (kk), (char*)&sB[nb][0]  + ldst + 8192);  \
        GLD16(srcB[3] + (kk), (char*)&sB[nb][0]  + ldst + 12288); \
        GLD16(srcA1[0] + (kk), (char*)&sA1[nb][0] + ldst + 0);    \
        GLD16(srcA1[1] + (kk), (char*)&sA1[nb][0] + ldst + 4096); \
        GLD16(srcA2[0] + (kk), (char*)&sA2[nb][0] + ldst + 0);    \
        GLD16(srcA2[1] + (kk), (char*)&sA2[nb][0] + ldst + 4096); \
        GLD16(srcA3[0] + (kk), (char*)&sA3[nb][0] + ldst + 0);    \
        GLD16(srcA3[1] + (kk), (char*)&sA3[nb][0] + ldst + 4096); \
    } while (0)

    // prologue: tile 0 into buf 0, drain, enter loop
    STAGE(0, 0);
    __syncthreads();

    for (int k0 = 0; k0 < KCH; k0 += 64) {
        const int cur = (k0 >> 6) & 1;
        if (k0 + 64 < KCH) STAGE(cur ^ 1, k0 + 64);   // issue next tile EARLY
        // ---- compute current tile ----
        const char* bb = (const char*)&sB[cur][0] + brow * 256u;
        const char* a1b = (const char*)&sA1[cur][0];
        const char* a2b = (const char*)&sA2[cur][0];
        const char* a3b = (const char*)&sA3[cur][0];
#pragma unroll
        for (int s = 0; s < 2; ++s) {
            unsigned binner = (unsigned)(s * 128 + q * 32);
            float4 bf0 = *(const float4*)(bb + (binner ^ bswz));
            float4 bf1 = *(const float4*)(bb + ((binner + 16u) ^ bswz));
            short8 vb1, vb2, vb3;
            splitB(bf0, bf1, vb1, vb2, vb3);
#pragma unroll
            for (int mf = 0; mf < 4; ++mf) {
                unsigned arow = (unsigned)(mf * 16 + lrow);
                unsigned abyte = arow * 128u
                               + (((unsigned)(s * 64 + q * 16)) ^ ((arow & 7u) << 4));
                short8 a1 = *(const short8*)(a1b + abyte);
                short8 a2 = *(const short8*)(a2b + abyte);
                short8 a3 = *(const short8*)(a3b + abyte);
                acc[mf] = __builtin_amdgcn_mfma_f32_16x16x32_bf16(a1, vb1, acc[mf], 0, 0, 0);
                acc[mf] = __builtin_amdgcn_mfma_f32_16x16x32_bf16(a1, vb2, acc[mf], 0, 0, 0);
                acc[mf] = __builtin_amdgcn_mfma_f32_16x16x32_bf16(a2, vb1, acc[mf], 0, 0, 0);
                acc[mf] = __builtin_amdgcn_mfma_f32_16x16x32_bf16(a2, vb2, acc[mf], 0, 0, 0);
                acc[mf] = __builtin_amdgcn_mfma_f32_16x16x32_bf16(a1, vb3, acc[mf], 0, 0, 0);
                acc[mf] = __builtin_amdgcn_mfma_f32_16x16x32_bf16(a3, vb1, acc[mf], 0, 0, 0);
            }
        }
        __syncthreads();   // drain next tile's loads + close reads of cur
    }
#undef STAGE
    float* pout = part + (size_t)kc * (B_SEQ * V_DIM);
#pragma unroll
    for (int mf = 0; mf < 4; ++mf)
#pragma unroll
        for (int r = 0; r < 4; ++r) {
            int m = mf * 16 + q * 4 + r;
            pout[(size_t)m * V_DIM + vrow] = acc[mf][r];
        }
}

__device__ __forceinline__ float4 f4add(float4 a, float4 b) {
    return make_float4(a.x + b.x, a.y + b.y, a.z + b.z, a.w + b.w);
}

// ---- deterministic split-K reduce + temperature divide + out_probs zeroing ----
__global__ void k_reduce(const float* __restrict__ part,
                         const float* __restrict__ temps,
                         float* __restrict__ logits,
                         float* __restrict__ out_probs) {
    const int b = blockIdx.y;
    float t = temps[b];
    if (t < 1e-5f) t = 1.0f;
    const float inv = 1.0f / t;
    const float4* p0 = (const float4*)(part + 0 * (size_t)(B_SEQ * V_DIM) + (size_t)b * V_DIM);
    const float4* p1 = (const float4*)(part + 1 * (size_t)(B_SEQ * V_DIM) + (size_t)b * V_DIM);
    const float4* p2 = (const float4*)(part + 2 * (size_t)(B_SEQ * V_DIM) + (size_t)b * V_DIM);
    const float4* p3 = (const float4*)(part + 3 * (size_t)(B_SEQ * V_DIM) + (size_t)b * V_DIM);
    float4* lo = (float4*)(logits + (size_t)b * V_DIM);
    float4* po = (float4*)(out_probs + (size_t)b * V_DIM);
    const float4 z4 = make_float4(0.f, 0.f, 0.f, 0.f);
    for (int i = blockIdx.x * 256 + threadIdx.x; i < V_DIM / 4; i += 2048) {
        float4 s = f4add(f4add(f4add(p0[i], p1[i]), p2[i]), p3[i]);
        lo[i] = make_float4(s.x * inv, s.y * inv, s.z * inv, s.w * inv);
        po[i] = z4;
    }
}

// ---- fused per-row sampler: ONE HBM scan, logits LDS-resident thereafter ----
__global__ __launch_bounds__(512) void k_sample(const float* __restrict__ logits,
                                                const int* __restrict__ tks,
                                                const float* __restrict__ tps,
                                                const float* __restrict__ uu,
                                                float* __restrict__ out_tok,
                                                float* __restrict__ out_probs) {
    const int b = blockIdx.x, t = threadIdx.x;
    const float* lr = logits + (size_t)b * V_DIM;
    __shared__ float lg[V_DIM];                 // 125 KB: the whole logit row
    __shared__ unsigned hist[2048];             // 8 KB (overlaid by sp after gather)
    __shared__ unsigned long long cand[MAXC];   // 16 KB
    __shared__ unsigned redu[512];
    __shared__ float redf[512];
    __shared__ unsigned s_sel1, s_ab1, s_thr, s_nc, s_ab2, s_kthkey;
    __shared__ float s_m, s_Z, s_tot;
    __shared__ int s_cnt, s_L, s_tok, s_nk;

    int k = tks[b];
    if (k < 1) k = 1;
    if (k > V_DIM) k = V_DIM;

    // ---- pass A (fused with the single HBM scan): load row -> LDS, max + top-11-bit hist
    for (int i = t; i < 2048; i += 512) hist[i] = 0u;
    __syncthreads();
    unsigned km = 0u;
    for (int v = t; v < V_DIM; v += 512) {
        float f = lr[v];
        lg[v] = f;
        unsigned key = f2key(f);
        km = max(km, key);
        atomicAdd(&hist[key >> 21], 1u);
    }
    redu[t] = km;
    __syncthreads();
    for (int s = 256; s > 0; s >>= 1) {
        if (t < s) redu[t] = max(redu[t], redu[t + s]);
        __syncthreads();
    }
    if (t == 0) s_m = key2f(redu[0]);
    __syncthreads();
    float m = s_m;
    redu[t] = hist[4 * t] + hist[4 * t + 1] + hist[4 * t + 2] + hist[4 * t + 3];
    __syncthreads();
    if (t == 0) {
        unsigned acc = 0; int g = 0; bool found = false;
        for (int g0 = 511; g0 >= 0 && !found; g0 -= 8) {
            unsigned v[8];
#pragma unroll
            for (int j = 0; j < 8; ++j) v[j] = redu[g0 - j];
#pragma unroll
            for (int j = 0; j < 8; ++j) {
                if (acc + v[j] >= (unsigned)k) { g = g0 - j; found = true; break; }
                acc += v[j];
            }
        }
        int sel = 4 * g;
        for (int bk = 4 * g + 3; bk >= 4 * g; --bk) {
            unsigned h = hist[bk];
            if (acc + h >= (unsigned)k) { sel = bk; break; }
            acc += h;
        }
        s_sel1 = (unsigned)sel; s_ab1 = acc;
    }
    __syncthreads();
    unsigned sel1 = s_sel1, ab1 = s_ab1;

    // ---- pass B (LDS): exp-sum + mid-11-bit histogram within sel1 ----
    for (int i = t; i < 2048; i += 512) hist[i] = 0u;
    __syncthreads();
    float es = 0.f;
    for (int v = t; v < V_DIM; v += 512) {
        float f = lg[v];
        es += expf(f - m);
        unsigned key = f2key(f);
        if ((key >> 21) == sel1) atomicAdd(&hist[(key >> 10) & 2047u], 1u);
    }
    redf[t] = es;
    __syncthreads();
    for (int s = 256; s > 0; s >>= 1) {
        if (t < s) redf[t] += redf[t + s];
        __syncthreads();
    }
    if (t == 0) s_Z = redf[0];
    __syncthreads();
    redu[t] = hist[4 * t] + hist[4 * t + 1] + hist[4 * t + 2] + hist[4 * t + 3];
    __syncthreads();
    if (t == 0) {
        unsigned kk = (unsigned)k - ab1;
        unsigned acc = 0; int g = 0; bool found = false;
        for (int g0 = 511; g0 >= 0 && !found; g0 -= 8) {
            unsigned v[8];
#pragma unroll
            for (int j = 0; j < 8; ++j) v[j] = redu[g0 - j];
#pragma unroll
            for (int j = 0; j < 8; ++j) {
                if (acc + v[j] >= kk) { g = g0 - j; found = true; break; }
                acc += v[j];
            }
        }
        int sel = 4 * g;
        for (int bk = 4 * g + 3; bk >= 4 * g; --bk) {
            unsigned h = hist[bk];
            if (acc + h >= kk) { sel = bk; break; }
            acc += h;
        }
        s_ab2 = ab1 + acc;
        s_thr = (sel1 << 21) | ((unsigned)sel << 10);
        s_nc = ab1 + acc + hist[sel];
    }
    __syncthreads();
    unsigned thr = s_thr;

    // ---- rare pass C (LDS): exact kth key if 22-bit bin too fat ----
    if (s_nc > (unsigned)MAXC) {
        for (int i = t; i < 1024; i += 512) hist[i] = 0u;
        __syncthreads();
        for (int v = t; v < V_DIM; v += 512) {
            unsigned key = f2key(lg[v]);
            if ((key & 0xFFFFFC00u) == thr) atomicAdd(&hist[key & 1023u], 1u);
        }
        __syncthreads();
        if (t == 0) {
            unsigned kk = (unsigned)k - s_ab2;
            unsigned acc = 0; int sel = 0;
            for (int bk = 1023; bk >= 0; --bk) {
                unsigned h = hist[bk];
                if (acc + h >= kk) { sel = bk; break; }
                acc += h;
            }
            s_thr = thr | (unsigned)sel;
        }
        __syncthreads();
        thr = s_thr;
    }

    // ---- gather candidates from LDS (key >= thr: superset of top-k incl. ties) ----
    if (t == 0) s_cnt = 0;
    for (int i = t; i < MAXC; i += 512) cand[i] = 0xFFFFFFFFFFFFFFFFULL;
    __syncthreads();
    for (int v = t; v < V_DIM; v += 512) {
        unsigned key = f2key(lg[v]);
        if (key >= thr) {
            int p = atomicAdd(&s_cnt, 1);
            if (p < MAXC) cand[p] = (((unsigned long long)(~key)) << 32) | (unsigned)v;
        }
    }
    __syncthreads();
    int n = s_cnt; if (n > MAXC) n = MAXC;
    const int np2 = (n <= 1) ? 1 : (1 << (32 - __clz(n - 1)));

    // ---- bitonic sort of the first np2 entries (key desc, idx asc) ----
    for (unsigned size = 2; size <= (unsigned)np2; size <<= 1)
        for (unsigned stride = size >> 1; stride > 0; stride >>= 1) {
            for (unsigned i = t; i < (unsigned)np2; i += 512) {
                unsigned j = i ^ stride;
                if (j > i) {
                    unsigned long long a = cand[i], c = cand[j];
                    bool up = ((i & size) == 0);
                    if (up ? (a > c) : (a < c)) { cand[i] = c; cand[j] = a; }
                }
            }
            __syncthreads();
        }
    // hist is dead from here: overlay sp on it (8 KB == 2048 floats)
    float* sp = (float*)hist;
    float Z = s_Z;
    for (int i = t; i < n; i += 512) {
        unsigned key = ~(unsigned)(cand[i] >> 32);
        sp[i] = expf(key2f(key) - m) / Z;
    }
    for (int i = n + t; i < MAXC; i += 512) sp[i] = 0.f;
    if (t == 0) s_kthkey = ~(unsigned)(cand[k - 1] >> 32);
    __syncthreads();

    // parallel top-k prefix length incl. ties
    unsigned kthkey = s_kthkey;
    int cnt = 0;
    for (int i = t; i < n; i += 512)
        if ((~(unsigned)(cand[i] >> 32)) >= kthkey) cnt++;
    redu[t] = (unsigned)cnt;
    __syncthreads();
    for (int s = 256; s > 0; s >>= 1) {
        if (t < s) redu[t] += redu[t + s];
        __syncthreads();
    }
    if (t == 0) s_nk = (int)redu[0];
    __syncthreads();

    if (t == 0) {
        float top_p = tps[b];
        bool keepall = (top_p >= 1.0f - 1e-5f);
        int limit = min(n, s_nk);
        // top-p prefix, numpy-sequential fp32, batched LDS preloads
        float c = 0.f; int L = limit; bool done = false;
        for (int i0 = 0; i0 < limit && !done; i0 += 8) {
            float v[8];
#pragma unroll
            for (int j = 0; j < 8; ++j) v[j] = sp[i0 + j];
#pragma unroll
            for (int j = 0; j < 8; ++j) {
                int i = i0 + j;
                if (i >= limit) { done = true; break; }
                float cum = c + v[j];
                if (!keepall && !((cum - v[j]) <= top_p)) { L = i; done = true; break; }
                c = cum;
            }
        }
        float total = c;
        float target = uu[b] * total;
        float c2 = 0.f; int jj = L - 1; done = false;
        for (int i0 = 0; i0 < L && !done; i0 += 8) {
            float v[8];
#pragma unroll
            for (int j = 0; j < 8; ++j) v[j] = sp[i0 + j];
#pragma unroll
            for (int j = 0; j < 8; ++j) {
                int i = i0 + j;
                if (i >= L) { done = true; break; }
                c2 += v[j];
                if (!(c2 < target)) { jj = i; done = true; break; }
            }
        }
        s_tok = (int)(cand[jj] & 0xFFFFFFFFULL);
        s_L = L; s_tot = total;
        out_tok[b] = (float)s_tok;
    }
    __syncthreads();
    int L = s_L; float total = s_tot;
    for (int i = t; i < L; i += 512) {
        unsigned v = (unsigned)(cand[i] & 0xFFFFFFFFULL);
        out_probs[(size_t)b * V_DIM + v] = sp[i] / total;
    }
}

extern "C" void kernel_launch(void* const* d_in, const int* in_sizes, int n_in,
                              void* d_out, int out_size, void* d_ws, size_t ws_size,
                              hipStream_t stream) {
    const float* hs    = (const float*)d_in[0];
    const float* emb   = (const float*)d_in[1];
    const float* temps = (const float*)d_in[2];
    const float* tps   = (const float*)d_in[3];
    const float* uu    = (const float*)d_in[4];
    const int*   lti   = (const int*)d_in[5];
    const int*   tks   = (const int*)d_in[6];

    float* ws = (float*)d_ws;
    ushort* h1 = (ushort*)(ws + H1_OFF);
    ushort* h2 = (ushort*)(ws + H2_OFF);
    ushort* h3 = (ushort*)(ws + H3_OFF);
    float* logits = ws + LOGITS_OFF;
    float* part   = ws + PART_OFF;

    float* out_tok   = (float*)d_out;
    float* out_probs = (float*)d_out + B_SEQ;

    k_prep<<<B_SEQ * 4, 256, 0, stream>>>(hs, lti, h1, h2, h3);
    k_gemm<<<dim3(V_DIM / 64, SPLITK), 256, 0, stream>>>(h1, h2, h3, emb, part);
    k_reduce<<<dim3(8, B_SEQ), 256, 0, stream>>>(part, temps, logits, out_probs);
    k_sample<<<B_SEQ, 512, 0, stream>>>(logits, tks, tps, uu, out_tok, out_probs);
}

// Round 13
// 299.365 us; speedup vs baseline: 1.0928x; 1.0922x over previous
//
#include <hip/hip_runtime.h>
#include <stdint.h>

#define D_DIM 4096
#define V_DIM 32000
#define B_SEQ 64
#define MAXC 2048
#define SPLITK 4
#define KCH 1024   // K per chunk

typedef __attribute__((ext_vector_type(8))) short short8;
typedef __attribute__((ext_vector_type(4))) float f32x4;

// ---- ws layout (float units) ----
#define H1_OFF     0u
#define H2_OFF     131072u
#define H3_OFF     262144u
#define LOGITS_OFF 393216u                     // 64*32000
#define PART_OFF   2441216u                    // 4 * 64*32000

// async global->LDS, 16B per lane, linear dest (wave-uniform base + lane*16)
#define GLD16(gsrc, ldst) \
    __builtin_amdgcn_global_load_lds((const __attribute__((address_space(1))) unsigned*)(gsrc), \
                                     (__attribute__((address_space(3))) unsigned*)(ldst), 16, 0, 0)

__device__ __forceinline__ unsigned f2key(float x) {
    unsigned u = __float_as_uint(x);
    return (u & 0x80000000u) ? ~u : (u | 0x80000000u);
}
__device__ __forceinline__ float key2f(unsigned k) {
    unsigned u = (k & 0x80000000u) ? (k & 0x7FFFFFFFu) : ~k;
    return __uint_as_float(u);
}
// exact truncation split: x == l1 + l2 + l3
__device__ __forceinline__ void split3(float x, ushort& a, ushort& b, ushort& c) {
    unsigned u = __float_as_uint(x);
    a = (ushort)(u >> 16);
    float r1 = x - __uint_as_float(u & 0xFFFF0000u);
    unsigned u2 = __float_as_uint(r1);
    b = (ushort)(u2 >> 16);
    float r2 = r1 - __uint_as_float(u2 & 0xFFFF0000u);
    c = (ushort)(__float_as_uint(r2) >> 16);
}

// ---- gather last-token rows + split into 3 exact bf16 limbs (4 blocks/row) ----
__global__ void k_prep(const float* __restrict__ hs, const int* __restrict__ lti,
                       ushort* __restrict__ h1, ushort* __restrict__ h2,
                       ushort* __restrict__ h3) {
    int b = blockIdx.x >> 2;
    int quarter = blockIdx.x & 3;
    int base = quarter * (D_DIM / 16);   // float4 units
    const float4* src = (const float4*)(hs + (size_t)lti[b] * D_DIM);
    ushort4* d1 = (ushort4*)(h1 + (size_t)b * D_DIM);
    ushort4* d2 = (ushort4*)(h2 + (size_t)b * D_DIM);
    ushort4* d3 = (ushort4*)(h3 + (size_t)b * D_DIM);
    int i = base + threadIdx.x;
    float4 v = src[i];
    float x[4] = {v.x, v.y, v.z, v.w};
    ushort l1[4], l2[4], l3[4];
#pragma unroll
    for (int j = 0; j < 4; ++j) split3(x[j], l1[j], l2[j], l3[j]);
    d1[i] = make_ushort4(l1[0], l1[1], l1[2], l1[3]);
    d2[i] = make_ushort4(l2[0], l2[1], l2[2], l2[3]);
    d3[i] = make_ushort4(l3[0], l3[1], l3[2], l3[3]);
}

__device__ __forceinline__ void splitB(const float4& x0, const float4& x1,
                                       short8& b1, short8& b2, short8& b3) {
    float xf[8] = {x0.x, x0.y, x0.z, x0.w, x1.x, x1.y, x1.z, x1.w};
#pragma unroll
    for (int j = 0; j < 8; ++j) {
        ushort u1, u2, u3;
        split3(xf[j], u1, u2, u3);
        b1[j] = (short)u1; b2[j] = (short)u2; b3[j] = (short)u3;
    }
}

// ---- split-K MFMA GEMM, 64M x 128N tile, single-buffer 56 KB, GLD staging ----
__global__ __launch_bounds__(256, 2) void k_gemm(const ushort* __restrict__ h1,
                                                 const ushort* __restrict__ h2,
                                                 const ushort* __restrict__ h3,
                                                 const float* __restrict__ emb,
                                                 float* __restrict__ part) {
    __shared__ __align__(16) float  sB[8192];   // 128 vocab rows x 64 k fp32 (32 KB)
    __shared__ __align__(16) ushort sA1[4096];  // 64 m x 64 k bf16 (8 KB) x 3 limbs
    __shared__ __align__(16) ushort sA2[4096];
    __shared__ __align__(16) ushort sA3[4096];
    const int tid = threadIdx.x;
    const int w = tid >> 6, lane = tid & 63, lrow = lane & 15, q = lane >> 4;
    const int kc = blockIdx.y;
    const int vbase = blockIdx.x * 128;
    const size_t kbase = (size_t)kc * KCH;

    f32x4 acc[4][2];
#pragma unroll
    for (int mf = 0; mf < 4; ++mf)
#pragma unroll
        for (int nf = 0; nf < 2; ++nf)
#pragma unroll
            for (int r = 0; r < 4; ++r) acc[mf][nf][r] = 0.f;

    // ---- staging descriptors (per-lane pre-swizzled global sources) ----
    // B: 32 KB = 8 instr/thread; instr j: LDS slot = w*1024 + j*4096 + lane*16
    const float* srcB[8];
#pragma unroll
    for (int j = 0; j < 8; ++j) {
        int row = w * 4 + j * 16 + (lane >> 4);
        unsigned c16 = (((unsigned)(lane & 15)) << 4) ^ (((unsigned)(row & 7)) << 4);
        srcB[j] = emb + (size_t)(vbase + row) * D_DIM + kbase + (c16 >> 2);
    }
    // A limbs: 8 KB each = 2 instr/thread
    const ushort* srcA1[2]; const ushort* srcA2[2]; const ushort* srcA3[2];
#pragma unroll
    for (int j = 0; j < 2; ++j) {
        int row = w * 8 + j * 32 + (lane >> 3);
        unsigned c16 = (((unsigned)(lane & 7)) << 4) ^ (((unsigned)(row & 7)) << 4);
        size_t off = (size_t)row * D_DIM + kbase + (c16 >> 1);
        srcA1[j] = h1 + off; srcA2[j] = h2 + off; srcA3[j] = h3 + off;
    }
    const unsigned ldst = (unsigned)(w * 1024);

    for (int k0 = 0; k0 < KCH; k0 += 64) {
        if (k0) __syncthreads();   // all reads of previous tile done
        // ---- stage tile k0 (async, no VGPR destination) ----
#pragma unroll
        for (int j = 0; j < 8; ++j)
            GLD16(srcB[j] + k0, (char*)sB + ldst + j * 4096);
#pragma unroll
        for (int j = 0; j < 2; ++j) {
            GLD16(srcA1[j] + k0, (char*)sA1 + ldst + j * 4096);
            GLD16(srcA2[j] + k0, (char*)sA2 + ldst + j * 4096);
            GLD16(srcA3[j] + k0, (char*)sA3 + ldst + j * 4096);
        }
        __syncthreads();           // tile resident
        // ---- compute ----
#pragma unroll
        for (int s = 0; s < 2; ++s) {
            short8 vb1[2], vb2[2], vb3[2];
#pragma unroll
            for (int nf = 0; nf < 2; ++nf) {
                unsigned brow = (unsigned)(w * 32 + nf * 16 + lrow);
                const char* bb = (const char*)sB + brow * 256u;
                unsigned bswz = (brow & 7u) << 4;
                unsigned binner = (unsigned)(s * 128 + q * 32);
                float4 bf0 = *(const float4*)(bb + (binner ^ bswz));
                float4 bf1 = *(const float4*)(bb + ((binner + 16u) ^ bswz));
                splitB(bf0, bf1, vb1[nf], vb2[nf], vb3[nf]);
            }
#pragma unroll
            for (int mf = 0; mf < 4; ++mf) {
                unsigned arow = (unsigned)(mf * 16 + lrow);
                unsigned abyte = arow * 128u
                               + (((unsigned)(s * 64 + q * 16)) ^ ((arow & 7u) << 4));
                short8 a1 = *(const short8*)((const char*)sA1 + abyte);
                short8 a2 = *(const short8*)((const char*)sA2 + abyte);
                short8 a3 = *(const short8*)((const char*)sA3 + abyte);
#pragma unroll
                for (int nf = 0; nf < 2; ++nf) {
                    acc[mf][nf] = __builtin_amdgcn_mfma_f32_16x16x32_bf16(a1, vb1[nf], acc[mf][nf], 0, 0, 0);
                    acc[mf][nf] = __builtin_amdgcn_mfma_f32_16x16x32_bf16(a1, vb2[nf], acc[mf][nf], 0, 0, 0);
                    acc[mf][nf] = __builtin_amdgcn_mfma_f32_16x16x32_bf16(a2, vb1[nf], acc[mf][nf], 0, 0, 0);
                    acc[mf][nf] = __builtin_amdgcn_mfma_f32_16x16x32_bf16(a2, vb2[nf], acc[mf][nf], 0, 0, 0);
                    acc[mf][nf] = __builtin_amdgcn_mfma_f32_16x16x32_bf16(a1, vb3[nf], acc[mf][nf], 0, 0, 0);
                    acc[mf][nf] = __builtin_amdgcn_mfma_f32_16x16x32_bf16(a3, vb1[nf], acc[mf][nf], 0, 0, 0);
                }
            }
        }
    }
    float* pout = part + (size_t)kc * (B_SEQ * V_DIM);
#pragma unroll
    for (int mf = 0; mf < 4; ++mf)
#pragma unroll
        for (int r = 0; r < 4; ++r) {
            int m = mf * 16 + q * 4 + r;
#pragma unroll
            for (int nf = 0; nf < 2; ++nf)
                pout[(size_t)m * V_DIM + vbase + w * 32 + nf * 16 + lrow] = acc[mf][nf][r];
        }
}

__device__ __forceinline__ float4 f4add(float4 a, float4 b) {
    return make_float4(a.x + b.x, a.y + b.y, a.z + b.z, a.w + b.w);
}

// ---- deterministic split-K reduce + temperature divide + out_probs zeroing ----
__global__ void k_reduce(const float* __restrict__ part,
                         const float* __restrict__ temps,
                         float* __restrict__ logits,
                         float* __restrict__ out_probs) {
    const int b = blockIdx.y;
    float t = temps[b];
    if (t < 1e-5f) t = 1.0f;
    const float inv = 1.0f / t;
    const float4* p0 = (const float4*)(part + 0 * (size_t)(B_SEQ * V_DIM) + (size_t)b * V_DIM);
    const float4* p1 = (const float4*)(part + 1 * (size_t)(B_SEQ * V_DIM) + (size_t)b * V_DIM);
    const float4* p2 = (const float4*)(part + 2 * (size_t)(B_SEQ * V_DIM) + (size_t)b * V_DIM);
    const float4* p3 = (const float4*)(part + 3 * (size_t)(B_SEQ * V_DIM) + (size_t)b * V_DIM);
    float4* lo = (float4*)(logits + (size_t)b * V_DIM);
    float4* po = (float4*)(out_probs + (size_t)b * V_DIM);
    const float4 z4 = make_float4(0.f, 0.f, 0.f, 0.f);
    for (int i = blockIdx.x * 256 + threadIdx.x; i < V_DIM / 4; i += 2048) {
        float4 s = f4add(f4add(f4add(p0[i], p1[i]), p2[i]), p3[i]);
        lo[i] = make_float4(s.x * inv, s.y * inv, s.z * inv, s.w * inv);
        po[i] = z4;
    }
}

// ---- fused per-row: max/Z + radix-select + gather + sort + top-p + sample ----
__global__ __launch_bounds__(512) void k_sample(const float* __restrict__ logits,
                                                const int* __restrict__ tks,
                                                const float* __restrict__ tps,
                                                const float* __restrict__ uu,
                                                float* __restrict__ out_tok,
                                                float* __restrict__ out_probs) {
    const int b = blockIdx.x, t = threadIdx.x;
    const float* lr = logits + (size_t)b * V_DIM;
    __shared__ unsigned hist[2048];
    __shared__ unsigned redu[512];
    __shared__ float redf[512];
    __shared__ unsigned long long cand[MAXC];
    __shared__ float sp[MAXC];
    __shared__ unsigned s_sel1, s_ab1, s_thr, s_nc, s_ab2, s_kthkey;
    __shared__ float s_m, s_Z, s_tot;
    __shared__ int s_cnt, s_L, s_tok, s_nk;

    int k = tks[b];
    if (k < 1) k = 1;
    if (k > V_DIM) k = V_DIM;

    // ---- pass A: max + top-11-bit histogram ----
    for (int i = t; i < 2048; i += 512) hist[i] = 0u;
    __syncthreads();
    unsigned km = 0u;
    for (int v = t; v < V_DIM; v += 512) {
        unsigned key = f2key(lr[v]);
        km = max(km, key);
        atomicAdd(&hist[key >> 21], 1u);
    }
    redu[t] = km;
    __syncthreads();
    for (int s = 256; s > 0; s >>= 1) {
        if (t < s) redu[t] = max(redu[t], redu[t + s]);
        __syncthreads();
    }
    if (t == 0) s_m = key2f(redu[0]);
    __syncthreads();
    float m = s_m;
    redu[t] = hist[4 * t] + hist[4 * t + 1] + hist[4 * t + 2] + hist[4 * t + 3];
    __syncthreads();
    if (t == 0) {
        unsigned acc = 0; int g = 0; bool found = false;
        for (int g0 = 511; g0 >= 0 && !found; g0 -= 8) {
            unsigned v[8];
#pragma unroll
            for (int j = 0; j < 8; ++j) v[j] = redu[g0 - j];
#pragma unroll
            for (int j = 0; j < 8; ++j) {
                if (acc + v[j] >= (unsigned)k) { g = g0 - j; found = true; break; }
                acc += v[j];
            }
        }
        int sel = 4 * g;
        for (int bk = 4 * g + 3; bk >= 4 * g; --bk) {
            unsigned h = hist[bk];
            if (acc + h >= (unsigned)k) { sel = bk; break; }
            acc += h;
        }
        s_sel1 = (unsigned)sel; s_ab1 = acc;
    }
    __syncthreads();
    unsigned sel1 = s_sel1, ab1 = s_ab1;

    // ---- pass B: exp-sum + mid-11-bit histogram within sel1 ----
    for (int i = t; i < 2048; i += 512) hist[i] = 0u;
    __syncthreads();
    float es = 0.f;
    for (int v = t; v < V_DIM; v += 512) {
        float f = lr[v];
        es += expf(f - m);
        unsigned key = f2key(f);
        if ((key >> 21) == sel1) atomicAdd(&hist[(key >> 10) & 2047u], 1u);
    }
    redf[t] = es;
    __syncthreads();
    for (int s = 256; s > 0; s >>= 1) {
        if (t < s) redf[t] += redf[t + s];
        __syncthreads();
    }
    if (t == 0) s_Z = redf[0];
    __syncthreads();
    redu[t] = hist[4 * t] + hist[4 * t + 1] + hist[4 * t + 2] + hist[4 * t + 3];
    __syncthreads();
    if (t == 0) {
        unsigned kk = (unsigned)k - ab1;
        unsigned acc = 0; int g = 0; bool found = false;
        for (int g0 = 511; g0 >= 0 && !found; g0 -= 8) {
            unsigned v[8];
#pragma unroll
            for (int j = 0; j < 8; ++j) v[j] = redu[g0 - j];
#pragma unroll
            for (int j = 0; j < 8; ++j) {
                if (acc + v[j] >= kk) { g = g0 - j; found = true; break; }
                acc += v[j];
            }
        }
        int sel = 4 * g;
        for (int bk = 4 * g + 3; bk >= 4 * g; --bk) {
            unsigned h = hist[bk];
            if (acc + h >= kk) { sel = bk; break; }
            acc += h;
        }
        s_ab2 = ab1 + acc;
        s_thr = (sel1 << 21) | ((unsigned)sel << 10);
        s_nc = ab1 + acc + hist[sel];
    }
    __syncthreads();
    unsigned thr = s_thr;

    // ---- rare pass C: exact kth key if 22-bit bin too fat ----
    if (s_nc > (unsigned)MAXC) {
        for (int i = t; i < 1024; i += 512) hist[i] = 0u;
        __syncthreads();
        for (int v = t; v < V_DIM; v += 512) {
            unsigned key = f2key(lr[v]);
            if ((key & 0xFFFFFC00u) == thr) atomicAdd(&hist[key & 1023u], 1u);
        }
        __syncthreads();
        if (t == 0) {
            unsigned kk = (unsigned)k - s_ab2;
            unsigned acc = 0; int sel = 0;
            for (int bk = 1023; bk >= 0; --bk) {
                unsigned h = hist[bk];
                if (acc + h >= kk) { sel = bk; break; }
                acc += h;
            }
            s_thr = thr | (unsigned)sel;
        }
        __syncthreads();
        thr = s_thr;
    }

    // ---- gather candidates (key >= thr: superset of top-k incl. ties) ----
    if (t == 0) s_cnt = 0;
    for (int i = t; i < MAXC; i += 512) cand[i] = 0xFFFFFFFFFFFFFFFFULL;
    __syncthreads();
    for (int v = t; v < V_DIM; v += 512) {
        unsigned key = f2key(lr[v]);
        if (key >= thr) {
            int p = atomicAdd(&s_cnt, 1);
            if (p < MAXC) cand[p] = (((unsigned long long)(~key)) << 32) | (unsigned)v;
        }
    }
    __syncthreads();
    int n = s_cnt; if (n > MAXC) n = MAXC;
    const int np2 = (n <= 1) ? 1 : (1 << (32 - __clz(n - 1)));

    // ---- bitonic sort of the first np2 entries (key desc, idx asc) ----
    for (unsigned size = 2; size <= (unsigned)np2; size <<= 1)
        for (unsigned stride = size >> 1; stride > 0; stride >>= 1) {
            for (unsigned i = t; i < (unsigned)np2; i += 512) {
                unsigned j = i ^ stride;
                if (j > i) {
                    unsigned long long a = cand[i], c = cand[j];
                    bool up = ((i & size) == 0);
                    if (up ? (a > c) : (a < c)) { cand[i] = c; cand[j] = a; }
                }
            }
            __syncthreads();
        }
    float Z = s_Z;
    for (int i = t; i < n; i += 512) {
        unsigned key = ~(unsigned)(cand[i] >> 32);
        sp[i] = expf(key2f(key) - m) / Z;
    }
    for (int i = n + t; i < MAXC; i += 512) sp[i] = 0.f;
    if (t == 0) s_kthkey = ~(unsigned)(cand[k - 1] >> 32);
    __syncthreads();

    // parallel top-k prefix length incl. ties
    unsigned kthkey = s_kthkey;
    int cnt = 0;
    for (int i = t; i < n; i += 512)
        if ((~(unsigned)(cand[i] >> 32)) >= kthkey) cnt++;
    redu[t] = (unsigned)cnt;
    __syncthreads();
    for (int s = 256; s > 0; s >>= 1) {
        if (t < s) redu[t] += redu[t + s];
        __syncthreads();
    }
    if (t == 0) s_nk = (int)redu[0];
    __syncthreads();

    if (t == 0) {
        float top_p = tps[b];
        bool keepall = (top_p >= 1.0f - 1e-5f);
        int limit = min(n, s_nk);
        // top-p prefix, numpy-sequential fp32, batched LDS preloads
        float c = 0.f; int L = limit; bool done = false;
        for (int i0 = 0; i0 < limit && !done; i0 += 8) {
            float v[8];
#pragma unroll
            for (int j = 0; j < 8; ++j) v[j] = sp[i0 + j];
#pragma unroll
            for (int j = 0; j < 8; ++j) {
                int i = i0 + j;
                if (i >= limit) { done = true; break; }
                float cum = c + v[j];
                if (!keepall && !((cum - v[j]) <= top_p)) { L = i; done = true; break; }
                c = cum;
            }
        }
        float total = c;
        float target = uu[b] * total;
        float c2 = 0.f; int jj = L - 1; done = false;
        for (int i0 = 0; i0 < L && !done; i0 += 8) {
            float v[8];
#pragma unroll
            for (int j = 0; j < 8; ++j) v[j] = sp[i0 + j];
#pragma unroll
            for (int j = 0; j < 8; ++j) {
                int i = i0 + j;
                if (i >= L) { done = true; break; }
                c2 += v[j];
                if (!(c2 < target)) { jj = i; done = true; break; }
            }
        }
        s_tok = (int)(cand[jj] & 0xFFFFFFFFULL);
        s_L = L; s_tot = total;
        out_tok[b] = (float)s_tok;
    }
    __syncthreads();
    int L = s_L; float total = s_tot;
    for (int i = t; i < L; i += 512) {
        unsigned v = (unsigned)(cand[i] & 0xFFFFFFFFULL);
        out_probs[(size_t)b * V_DIM + v] = sp[i] / total;
    }
}

extern "C" void kernel_launch(void* const* d_in, const int* in_sizes, int n_in,
                              void* d_out, int out_size, void* d_ws, size_t ws_size,
                              hipStream_t stream) {
    const float* hs    = (const float*)d_in[0];
    const float* emb   = (const float*)d_in[1];
    const float* temps = (const float*)d_in[2];
    const float* tps   = (const float*)d_in[3];
    const float* uu    = (const float*)d_in[4];
    const int*   lti   = (const int*)d_in[5];
    const int*   tks   = (const int*)d_in[6];

    float* ws = (float*)d_ws;
    ushort* h1 = (ushort*)(ws + H1_OFF);
    ushort* h2 = (ushort*)(ws + H2_OFF);
    ushort* h3 = (ushort*)(ws + H3_OFF);
    float* logits = ws + LOGITS_OFF;
    float* part   = ws + PART_OFF;

    float* out_tok   = (float*)d_out;
    float* out_probs = (float*)d_out + B_SEQ;

    k_prep<<<B_SEQ * 4, 256, 0, stream>>>(hs, lti, h1, h2, h3);
    k_gemm<<<dim3(V_DIM / 128, SPLITK), 256, 0, stream>>>(h1, h2, h3, emb, part);
    k_reduce<<<dim3(8, B_SEQ), 256, 0, stream>>>(part, temps, logits, out_probs);
    k_sample<<<B_SEQ, 512, 0, stream>>>(logits, tks, tps, uu, out_tok, out_probs);
}